// Round 8
// baseline (822.943 us; speedup 1.0000x reference)
//
#include <hip/hip_runtime.h>
#include <math.h>

#define BATCH 4
#define HH 512
#define WW 1024
#define NPIX (HH*WW)          // 524288 = 2^19
#define CCAP 196608           // compaction capacity per image (expected ~161.7k valid)
#define GX 64
#define GY 48
#define NCELL (GX*GY)         // 3072 cells, 0.0625 x 0.0625 over [-1,3]x[-1,2]
#define CELL 0.0625f
#define INVCELL 16.0f
#define SEGSZ 512             // pixels per argmax-cache segment
#define NSEGMAX (CCAP/SEGSZ)  // 384
#define DLCAP 2048            // dirty-segment list capacity
#define CKCAP 800             // 256-px chunk queue capacity (worst case 792)
#define CKBCAP 512            // chunks with cached proposal ballot bits

// ---------------- XLA:CPU f32 math replicas (unchanged from passing rounds) ----
__device__ __forceinline__ float xla_tanhf(float x) {
  if (fabsf(x) < 0.0004f) return x;
  float xc = fminf(fmaxf(x, -7.90531110763549805f), 7.90531110763549805f);
  float x2 = __fmul_rn(xc, xc);
  float p = -2.76076847742355e-16f;
  p = fmaf(x2, p, 2.00018790482477e-13f);
  p = fmaf(x2, p, -8.60467152213735e-11f);
  p = fmaf(x2, p, 5.12229709037114e-08f);
  p = fmaf(x2, p, 1.48572235717979e-05f);
  p = fmaf(x2, p, 6.37261928875436e-04f);
  p = fmaf(x2, p, 4.89352455891786e-03f);
  p = __fmul_rn(xc, p);
  float q = fmaf(x2, 1.19825839466702e-06f, 1.18534705686654e-04f);
  q = fmaf(x2, q, 2.26843463243900e-03f);
  q = fmaf(x2, q, 4.89352518554385e-03f);
  return __fdiv_rn(p, q);
}

__device__ __forceinline__ float xla_expf(float x) {
  float xc = fminf(fmaxf(x, -87.3365478515625f), 88.72283935546875f);
  float m = floorf(fmaf(xc, 1.44269504088896341f, 0.5f));
  float r = fmaf(m, -0.693359375f, xc);
  r = fmaf(m, 2.12194440e-4f, r);
  float r2 = __fmul_rn(r, r);
  float p = 1.9875691500e-4f;
  p = fmaf(p, r, 1.3981999507e-3f);
  p = fmaf(p, r, 8.3334519073e-3f);
  p = fmaf(p, r, 4.1665795894e-2f);
  p = fmaf(p, r, 1.6666665459e-1f);
  p = fmaf(p, r, 5.0000001201e-1f);
  float y = fmaf(r2, p, r);
  y = __fadd_rn(y, 1.0f);
  return ldexpf(y, (int)m);
}

__device__ __forceinline__ float xla_sigmoidf(float x) {
  return fmaf(0.5f, xla_tanhf(__fmul_rn(0.5f, x)), 0.5f);
}

// Proposal test — byte-identical decision logic to the passing kernels.
__device__ __forceinline__ bool prop_test(float2 e, float cx, float cy,
                                          float den0, float den1,
                                          float inv0, float inv1) {
  float d0 = __fsub_rn(e.x, cx), d1 = __fsub_rn(e.y, cy);
  float dd0 = __fmul_rn(d0, d0), dd1 = __fmul_rn(d1, d1);
  float zf = fmaf(dd0, inv0, __fmul_rn(dd1, inv1));
  if (zf < 0.6921472f) return true;
  if (zf <= 0.6941472f) {
    float t0 = __fdiv_rn(dd0, den0);
    float t1 = __fdiv_rn(dd1, den1);
    float z = __fadd_rn(t0, t1);
    return xla_expf(-z) > 0.5f;
  }
  return false;
}

__device__ __forceinline__ int cell_of_x(float ex) {
  int c = (int)((ex + 1.0f) * INVCELL);
  return min(max(c, 0), GX - 1);
}
__device__ __forceinline__ int cell_of_y(float ey) {
  int c = (int)((ey + 1.0f) * INVCELL);
  return min(max(c, 0), GY - 1);
}

// bits [a,b) of a 64-bit mask; requires 0 <= a < 64, 0 <= b <= 64, a <= b.
__device__ __forceinline__ unsigned long long maskrange64(int a, int b) {
  unsigned long long mb = (b >= 64) ? ~0ULL : ((1ULL << b) - 1ULL);
  unsigned long long ma = (1ULL << a) - 1ULL;
  return mb & ~ma;
}

// ---------------- DPP wave64 primitives (VALU-speed, replaces DS shfl chains) --
// Standard rocPRIM sequence: row_shr 1/2/4/8 then row_bcast15 (rows 1,3) and
// row_bcast31 (rows 2,3). Reduce result lands in lane 63; readlane broadcasts.
__device__ __forceinline__ unsigned wave_max_bcast_u32(unsigned x) {
  unsigned t;
  t = (unsigned)__builtin_amdgcn_update_dpp(0, (int)x, 0x111, 0xf, 0xf, false); if (t > x) x = t;
  t = (unsigned)__builtin_amdgcn_update_dpp(0, (int)x, 0x112, 0xf, 0xf, false); if (t > x) x = t;
  t = (unsigned)__builtin_amdgcn_update_dpp(0, (int)x, 0x114, 0xf, 0xf, false); if (t > x) x = t;
  t = (unsigned)__builtin_amdgcn_update_dpp(0, (int)x, 0x118, 0xf, 0xf, false); if (t > x) x = t;
  t = (unsigned)__builtin_amdgcn_update_dpp(0, (int)x, 0x142, 0xa, 0xf, false); if (t > x) x = t;
  t = (unsigned)__builtin_amdgcn_update_dpp(0, (int)x, 0x143, 0xc, 0xf, false); if (t > x) x = t;
  return (unsigned)__builtin_amdgcn_readlane((int)x, 63);
}

__device__ __forceinline__ int wave_sum_bcast_i32(int x) {
  x += __builtin_amdgcn_update_dpp(0, x, 0x111, 0xf, 0xf, false);
  x += __builtin_amdgcn_update_dpp(0, x, 0x112, 0xf, 0xf, false);
  x += __builtin_amdgcn_update_dpp(0, x, 0x114, 0xf, 0xf, false);
  x += __builtin_amdgcn_update_dpp(0, x, 0x118, 0xf, 0xf, false);
  x += __builtin_amdgcn_update_dpp(0, x, 0x142, 0xa, 0xf, false);
  x += __builtin_amdgcn_update_dpp(0, x, 0x143, 0xc, 0xf, false);
  return __builtin_amdgcn_readlane(x, 63);
}

__device__ __forceinline__ int wave_scan_incl_i32(int x) {   // per-lane inclusive
  x += __builtin_amdgcn_update_dpp(0, x, 0x111, 0xf, 0xf, false);
  x += __builtin_amdgcn_update_dpp(0, x, 0x112, 0xf, 0xf, false);
  x += __builtin_amdgcn_update_dpp(0, x, 0x114, 0xf, 0xf, false);
  x += __builtin_amdgcn_update_dpp(0, x, 0x118, 0xf, 0xf, false);
  x += __builtin_amdgcn_update_dpp(0, x, 0x142, 0xa, 0xf, false);
  x += __builtin_amdgcn_update_dpp(0, x, 0x143, 0xc, 0xf, false);
  return x;
}

// Wave-uniform argmax over s_segkey[0..NSEG), optionally skipping one segment.
// DPP u32-score fast reduce + exact 64-bit shfl fallback on score ties (keys
// are pixel-unique). Returns sg=-1/key=0 when all (non-skipped) keys are 0.
__device__ __forceinline__ void seg_argmax(const unsigned long long* s_segkey,
                                           int NSEG, int lane, int skip,
                                           int &outSg, unsigned long long &outKey) {
  unsigned long long lk = 0ULL; int lsg = -1;
  for (int s = lane; s < NSEG; s += 64) {
    if (s == skip) continue;
    unsigned long long v = s_segkey[s];
    if (v > lk) { lk = v; lsg = s; }
  }
  unsigned ls = (unsigned)(lk >> 32);
  unsigned gs = wave_max_bcast_u32(ls);
  if (gs == 0u) { outSg = -1; outKey = 0ULL; return; }
  unsigned long long bmask = __ballot(ls == gs);
  if (__popcll(bmask) == 1ULL) {       // unique score -> that lane's key is max
    int src = __builtin_ctzll(bmask);
    outSg = __shfl(lsg, src);
    outKey = __shfl(lk, src);
  } else {                             // score tie: exact 64-bit fallback
    unsigned long long gk = lk;
    #pragma unroll
    for (int o = 1; o < 64; o <<= 1) {
      unsigned long long ok = __shfl_xor(gk, o);
      if (ok > gk) gk = ok;
    }
    unsigned long long bm2 = __ballot(lk == gk);   // keys unique -> one lane
    int src = __builtin_ctzll(bm2);
    outSg = __shfl(lsg, src);
    outKey = gk;
  }
}

// ---------------- kernels ----------------

__global__ __launch_bounds__(1024) void fill_kernel(int* out, int val, int n) {
  int i = blockIdx.x * 1024 + threadIdx.x;
  if (i < n) out[i] = val;
}

// pass A: zero output, LDS-aggregated histogram (one global atomic per block+cell)
__global__ __launch_bounds__(1024) void hist_kernel(const float* __restrict__ in,
                                                    int* __restrict__ out,
                                                    int* __restrict__ hist) {
  __shared__ int lh[NCELL];
  int tid = threadIdx.x;
  int gid = blockIdx.x * 1024 + tid;
  int b = gid >> 19;
  int p = gid & (NPIX - 1);
  for (int j = tid; j < NCELL; j += 1024) lh[j] = 0;
  __syncthreads();
  const float* base = in + (size_t)b * 5 * NPIX;
  float seed = base[(size_t)4 * NPIX + p];
  out[gid] = 0;
  if (seed > 0.5f) {
    float ox = base[p];
    float oy = base[(size_t)NPIX + p];
    int col = p & (WW - 1);
    int row = p >> 10;
    float gx = __fmul_rn((float)col, 2.0f / 1023.0f);
    float gy = __fmul_rn((float)row, 1.0f / 511.0f);
    float ex = __fadd_rn(xla_tanhf(ox), gx);
    float ey = __fadd_rn(xla_tanhf(oy), gy);
    atomicAdd(&lh[cell_of_y(ey) * GX + cell_of_x(ex)], 1);
  }
  __syncthreads();
  for (int j = tid; j < NCELL; j += 1024) {
    int c = lh[j];
    if (c) atomicAdd(&hist[b * NCELL + j], c);
  }
}

// pass B: exclusive scan of the cell counts per image (one block per image)
__global__ __launch_bounds__(1024) void scan_kernel(const int* __restrict__ hist,
                                                    int* __restrict__ off,
                                                    int* __restrict__ cursor) {
  __shared__ int s_c[NCELL];
  __shared__ int s_ps[1024];
  int b = blockIdx.x, t = threadIdx.x;
  const int* h = hist + b * NCELL;
  for (int i = t; i < NCELL; i += 1024) s_c[i] = h[i];
  __syncthreads();
  int a = s_c[3 * t], b2 = s_c[3 * t + 1], c2 = s_c[3 * t + 2];
  int th = a + b2 + c2;
  s_ps[t] = th;
  __syncthreads();
  for (int d = 1; d < 1024; d <<= 1) {
    int v = (t >= d) ? s_ps[t - d] : 0;
    __syncthreads();
    s_ps[t] += v;
    __syncthreads();
  }
  int excl = s_ps[t] - th;
  int* ob = off + b * (NCELL + 1);
  int* cb = cursor + b * NCELL;
  ob[3 * t] = excl;              cb[3 * t] = excl;
  ob[3 * t + 1] = excl + a;      cb[3 * t + 1] = excl + a;
  ob[3 * t + 2] = excl + a + b2; cb[3 * t + 2] = excl + a + b2;
  if (t == 1023) ob[NCELL] = s_ps[1023];
}

// pass C: LDS-aggregated scatter (within-cell order arbitrary; downstream is
// order-independent, tiebreak uses global pixel index)
__global__ __launch_bounds__(1024) void scatter_kernel(const float* __restrict__ in,
                                                       int* __restrict__ cursor,
                                                       float2* __restrict__ emb,
                                                       int2* __restrict__ pk) {
  __shared__ int lh[NCELL];
  __shared__ int lbase[NCELL];
  int tid = threadIdx.x;
  int gid = blockIdx.x * 1024 + tid;
  int b = gid >> 19;
  int p = gid & (NPIX - 1);
  for (int j = tid; j < NCELL; j += 1024) lh[j] = 0;
  __syncthreads();
  const float* base = in + (size_t)b * 5 * NPIX;
  float seed = base[(size_t)4 * NPIX + p];
  bool valid = seed > 0.5f;
  float ex = 0.0f, ey = 0.0f, smv = 0.0f;
  int cell = 0, sl = 0;
  if (valid) {
    float ox = base[p];
    float oy = base[(size_t)NPIX + p];
    int col = p & (WW - 1);
    int row = p >> 10;
    float gx = __fmul_rn((float)col, 2.0f / 1023.0f);
    float gy = __fmul_rn((float)row, 1.0f / 511.0f);
    ex = __fadd_rn(xla_tanhf(ox), gx);
    ey = __fadd_rn(xla_tanhf(oy), gy);
    smv = xla_sigmoidf(seed);
    cell = cell_of_y(ey) * GX + cell_of_x(ex);
    sl = atomicAdd(&lh[cell], 1);
  }
  __syncthreads();
  for (int j = tid; j < NCELL; j += 1024) {
    int c = lh[j];
    if (c) lbase[j] = atomicAdd(&cursor[b * NCELL + j], c);
  }
  __syncthreads();
  if (valid) {
    int slot = lbase[cell] + sl;
    if (slot < CCAP) {
      emb[(size_t)b * CCAP + slot] = make_float2(ex, ey);
      pk[(size_t)b * CCAP + slot]  = make_int2(__float_as_int(smv), p);
    }
  }
}

// Segment scan helper (SEGSZ=512: 8 strips of 64). DPP 32-bit-score reduce
// (exact 64-bit shfl fallback on score ties — keys are globally unique via
// ~pixel-index low bits). The unique winner lane precomputes reciprocal/radius
// aux2 so the broadcast path after argmax has no div/sqrt.
// Invariant: segkey[s] is EXACT while segment s's winner pixel is alive —
// non-winner removals cannot change the segment max, and winner removals
// force s onto the dirty list (exact rescan). Keys are pixel-unique, so
// "segkey unchanged across a rescan window" <=> same winner pixel, still alive.
__device__ __forceinline__ void seg_rescan(int s, int V, int lane,
    const unsigned* s_uncl, const int2* __restrict__ pk,
    const float2* __restrict__ emb, const float* __restrict__ base,
    unsigned long long* s_segkey, int* s_segci, float4* s_segaux,
    float4* s_segaux2, bool checkAlive) {
  unsigned long long bk = 0ULL; int bci = -1; int bpx = 0;
  #pragma unroll
  for (int j = 0; j < 8; ++j) {
    int i = (s << 9) + (j << 6) + lane;
    if (i < V) {
      bool alive = !checkAlive || ((s_uncl[i >> 5] >> (i & 31)) & 1u);
      if (alive) {
        int2 v = pk[i];
        unsigned long long k = ((unsigned long long)(unsigned)v.x << 32) | (unsigned)(~v.y);
        if (k > bk) { bk = k; bci = i; bpx = v.y; }
      }
    }
  }
  unsigned bs = (unsigned)(bk >> 32);
  unsigned ms = wave_max_bcast_u32(bs);
  if (ms == 0u) {                       // segment fully dead
    if (lane == 0) { s_segkey[s] = 0ULL; s_segci[s] = -1; }
    return;
  }
  unsigned long long tie = __ballot(bs == ms);
  bool winner;
  if (__popcll(tie) == 1ULL) {
    winner = (bs == ms);
  } else {
    unsigned long long mk = bk;
    #pragma unroll
    for (int o = 1; o < 64; o <<= 1) {
      unsigned long long ok = __shfl_xor(mk, o);
      if (ok > mk) mk = ok;
    }
    winner = (bk == mk);                // keys unique -> exactly one lane
  }
  if (winner) {
    s_segkey[s] = bk; s_segci[s] = bci;
    float2 e = emb[bci];
    float sxv = base[(size_t)2 * NPIX + bpx];
    float syv = base[(size_t)3 * NPIX + bpx];
    float d0 = __fmul_rn(2.0f, __fmul_rn(sxv, sxv));   // ref: 2.0 * s**2
    float d1 = __fmul_rn(2.0f, __fmul_rn(syv, syv));
    s_segaux[s] = make_float4(e.x, e.y, d0, d1);
    float i0v = 1.0f / d0;              // same expr as old broadcast path
    float i1v = 1.0f / d1;
    float ryv = sqrtf(__fmul_rn(d1, 0.6971472f)) * 1.00001f;
    s_segaux2[s] = make_float4(i0v, i1v, ryv, 0.0f);
  }
}

// One workgroup per image. 2 barriers/iteration. Pass-1 work is a flat 256-px
// 32-aligned chunk queue of packed u64 descriptors
// {i0>>5 | ss<<13 | lo<<19 | h2<<28 | en<<37} (chunk-relative clamped bounds;
// [ss,en) is this chunk's owned pixel range). Queue built redundantly per wave
// (benign identical-value LDS races), consumed round-robin by all 16 waves
// with 1-deep descriptor prefetch. Interior chunks use ANALYTIC range masks.
// Boundary-chunk ballots are cached (s_ckbA/s_ckbB) for label replay.
//
// NEW (R8): the NEXT round's argmax is computed SPECULATIVELY before B1
// (stale segkey, excluding current winner sg — segkey is only written by
// rescans, which happen after B1, so the stale view is stable). After B2 the
// speculation is validated with two broadcast LDS reads:
//   - dirty segments != sg have new keys <= old keys <= staleKey, so if
//     segkey[staleArg] is unchanged, the true next max is
//     max(staleKey, segkey[sg]) (sg's own segment is the only one whose new
//     key can exceed staleKey — its old key was the global max).
//   - if segkey[staleArg] changed (staleArg's winner died this round), fall
//     back to a full scan. Worst case == old behavior.
__global__ __launch_bounds__(1024) void cluster_kernel(const float* __restrict__ in,
                                                       int* __restrict__ out,
                                                       const float2* __restrict__ emb_all,
                                                       const int2* __restrict__ pk_all,
                                                       const int* __restrict__ off_g) {
  __shared__ unsigned int s_uncl[CCAP / 32];            // 24 KB
  __shared__ int s_off[NCELL + 1];                      // 12 KB
  __shared__ unsigned long long s_segkey[NSEGMAX];      // 3 KB
  __shared__ int s_segci[NSEGMAX];                      // 1.5 KB
  __shared__ float4 s_segaux[NSEGMAX];                  // 6 KB
  __shared__ float4 s_segaux2[NSEGMAX];                 // 6 KB (inv0,inv1,ry)
  __shared__ int s_dlist[DLCAP];                        // 8 KB
  __shared__ unsigned long long s_ck[CKCAP];            // 6.4 KB packed chunks
  __shared__ ulonglong2 s_ckbA[CKBCAP];                 // 8 KB ballots g0,g1
  __shared__ ulonglong2 s_ckbB[CKBCAP];                 // 8 KB ballots g2,g3
  __shared__ int s_pc[2];
  __shared__ int s_uc[2];
  __shared__ int s_nd[2];

  int b = blockIdx.x;
  int tid = threadIdx.x;
  int lane = tid & 63;
  int wid = tid >> 6;
  const int* offb = off_g + b * (NCELL + 1);
  int V = offb[NCELL];
  const float2* emb = emb_all + (size_t)b * CCAP;
  const int2*   pk  = pk_all  + (size_t)b * CCAP;
  int* outb = out + (size_t)b * NPIX;
  const float* base = in + (size_t)b * 5 * NPIX;

  if (V > CCAP) {   // capacity overflow marker
    for (int i = tid; i < NPIX; i += 1024) outb[i] = 1000000;
    return;
  }
  int NSEG = (V + SEGSZ - 1) >> 9;
  int Vm1 = V - 1;

  for (int i = tid; i <= NCELL; i += 1024) s_off[i] = offb[i];
  for (int w = tid; w < CCAP / 32; w += 1024) {
    int basebit = w << 5;
    unsigned m;
    if (basebit + 32 <= V)      m = 0xffffffffu;
    else if (basebit >= V)      m = 0u;
    else                        m = (1u << (V - basebit)) - 1u;
    s_uncl[w] = m;
  }
  if (tid < 2) { s_pc[tid] = 0; s_uc[tid] = 0; s_nd[tid] = 0; }
  __syncthreads();

  // build segment caches (all pixels alive)
  for (int s = wid; s < NSEG; s += 16)
    seg_rescan(s, V, lane, s_uncl, pk, emb, base, s_segkey, s_segci, s_segaux,
               s_segaux2, false);
  __syncthreads();

  int ucount = V, count = 1, guard = 0;
  int t = 0;
  int sg; unsigned long long sgKey;
  seg_argmax(s_segkey, NSEG, lane, -1, sg, sgKey);   // initial full scan
  while (ucount > 64 && guard++ <= CCAP) {
    if (sg < 0) break;
    if (__uint_as_float((unsigned)(sgKey >> 32)) < 0.5f) break;  // ref new_done
    int cur = t & 1, nxt = cur ^ 1;

    float4 aux = s_segaux[sg];         // broadcast LDS reads
    float4 ax2 = s_segaux2[sg];
    float cx = aux.x, cy = aux.y, den0 = aux.z, den1 = aux.w;
    float inv0 = ax2.x;
    float inv1 = ax2.y;
    float ry = ax2.z;
    int r0 = cell_of_y(cy - ry);
    int r1 = cell_of_y(cy + ry);
    int nr = r1 - r0 + 1;              // <= 19

    // ---- per-lane row geometry + packed chunk queue build (redundant) ----
    int ck = 0, rs_l = 0, re_l = 0, m0_l = 0, m1_l = 0, startl = 0;
    if (lane < nr) {
      int r = r0 + lane;
      float ylo = fmaf((float)r, CELL, -1.0f);
      float dy = fmaxf(0.0f, fmaxf(ylo - cy, cy - (ylo + CELL))) * 0.999999f;
      float rem = 0.6971472f - dy * dy * inv1;
      if (rem > 0.0f) {
        float dxm = sqrtf(den0 * rem) * 1.00001f;
        int c0 = cell_of_x(cx - dxm), c1 = cell_of_x(cx + dxm);
        int rbase = r * GX;
        rs_l = s_off[rbase + c0]; re_l = s_off[rbase + c1 + 1];
        m0_l = rs_l; m1_l = rs_l;
        float dyc = fmaxf(fabsf(ylo - cy), fabsf(ylo + CELL - cy)) + 1e-5f;
        float remI = 0.6920f - dyc * dyc * inv1;
        if (remI > 0.0f) {
          float dxin = sqrtf(den0 * remI) * 0.9999f;
          int a  = (int)ceilf(fmaf(cx - dxin, INVCELL, INVCELL) + 1e-3f);
          int bb = (int)floorf(fmaf(cx + dxin, INVCELL, INVCELL) - 1e-3f) - 1;
          a = max(a, c0); bb = min(bb, c1);
          if (a <= bb) { m0_l = s_off[rbase + a]; m1_l = s_off[rbase + bb + 1]; }
        }
        startl = rs_l & ~31;
        ck = (re_l > rs_l) ? ((re_l - startl + 255) >> 8) : 0;
      }
    }
    int cum = wave_scan_incl_i32(ck);   // DPP inclusive scan (lanes>=nr add 0)
    int nc = __builtin_amdgcn_readlane(cum, 63);
    int excl = cum - ck;
    if (lane < nr && ck) {
      for (int k = 0; k < ck; ++k) {
        int i0k = startl + (k << 8);
        int ssk = max(rs_l - i0k, 0);                 // <=31, only k=0 nonzero
        int lok = min(max(m0_l - i0k, 0), 256);
        int h2k = min(max(m1_l - i0k, 0), 256);
        int enk = min(re_l - i0k, 256);
        s_ck[excl + k] = (unsigned long long)(unsigned)(i0k >> 5)
                       | ((unsigned long long)(unsigned)ssk << 13)
                       | ((unsigned long long)(unsigned)lok << 19)
                       | ((unsigned long long)(unsigned)h2k << 28)
                       | ((unsigned long long)(unsigned)enk << 37);
      }
    }

    // ---- pass 1: chunk queue, all waves round-robin, 1-deep prefetch ----
    int pc = 0, uc = 0;
    int c = wid;
    unsigned long long ed = (c < nc) ? s_ck[c] : 0ULL;
    while (c < nc) {
      int cn = c + 16;
      unsigned long long epre = (cn < nc) ? s_ck[cn] : 0ULL;
      int i0 = ((int)(ed & 0x1fff)) << 5;
      int ss = (int)((ed >> 13) & 0x3f);
      int lo = (int)((ed >> 19) & 0x1ff);
      int h2 = (int)((ed >> 28) & 0x1ff);
      int en = (int)((ed >> 37) & 0x1ff);
      bool interior = (lo <= ss && h2 >= en);
      unsigned long long bm0, bm1, bm2, bm3;
      if (interior) {                   // analytic masks: no loads, no ballots
        bm0 = maskrange64(ss, min(en, 64));
        bm1 = maskrange64(0, min(max(en - 64, 0), 64));
        bm2 = maskrange64(0, min(max(en - 128, 0), 64));
        bm3 = maskrange64(0, min(max(en - 192, 0), 64));
      } else {
        int idx1 = lane + 64, idx2 = lane + 128, idx3 = lane + 192;
        int ia = min(i0 + lane, Vm1),  ib = min(i0 + idx1, Vm1);
        int ic = min(i0 + idx2, Vm1),  id = min(i0 + idx3, Vm1);
        float2 e0 = emb[ia], e1 = emb[ib], e2 = emb[ic], e3 = emb[id];
        bool t0 = prop_test(e0, cx, cy, den0, den1, inv0, inv1);
        bool t1 = prop_test(e1, cx, cy, den0, den1, inv0, inv1);
        bool t2 = prop_test(e2, cx, cy, den0, den1, inv0, inv1);
        bool t3 = prop_test(e3, cx, cy, den0, den1, inv0, inv1);
        bool p0 = (lane >= ss && lane < en) && ((lane >= lo && lane < h2) || t0);
        bool p1 = (idx1 < en) && ((idx1 >= lo && idx1 < h2) || t1);
        bool p2 = (idx2 < en) && ((idx2 >= lo && idx2 < h2) || t2);
        bool p3 = (idx3 < en) && ((idx3 >= lo && idx3 < h2) || t3);
        bm0 = __ballot(p0);
        bm1 = __ballot(p1);
        bm2 = __ballot(p2);
        bm3 = __ballot(p3);
        if (c < CKBCAP) {
          if (lane == 0)      { ulonglong2 v; v.x = bm0; v.y = bm1; s_ckbA[c] = v; }
          else if (lane == 1) { ulonglong2 v; v.x = bm2; v.y = bm3; s_ckbB[c] = v; }
        }
      }
      if ((bm0 | bm1 | bm2 | bm3) != 0ULL && lane < 8) {
        unsigned long long bsel = (lane < 2) ? bm0 : (lane < 4) ? bm1
                                 : (lane < 6) ? bm2 : bm3;
        unsigned bits = (unsigned)(bsel >> ((lane & 1) << 5));
        pc += __popc(bits);
        if (bits) {
          unsigned tw = (unsigned)(i0 >> 5) + (unsigned)lane;
          unsigned old = atomicAnd(&s_uncl[tw], ~bits);
          unsigned remv = old & bits;
          if (remv) {
            uc += __popc(remv);
            int seg = (int)(tw >> 4);           // 512 px = 16 words
            int ciw = s_segci[seg];
            if ((ciw >> 5) == (int)tw && ((remv >> (ciw & 31)) & 1u)) {
              int pos = atomicAdd(&s_nd[cur], 1);
              if (pos < DLCAP) s_dlist[pos] = seg;
            }
          }
        }
      }
      c = cn; ed = epre;
    }

    // ---- speculative next-argmax over STALE segkey, excluding sg ----
    // segkey is only written by rescans (after B1); stable here.
    int staleArg; unsigned long long staleKey;
    seg_argmax(s_segkey, NSEG, lane, sg, staleArg, staleKey);

    int pcW = wave_sum_bcast_i32(pc);
    int ucW = wave_sum_bcast_i32(uc);
    if (lane == 0 && (pcW | ucW)) {
      if (pcW) atomicAdd(&s_pc[cur], pcW);
      if (ucW) atomicAdd(&s_uc[cur], ucW);
    }
    __syncthreads();   // B1

    int pcT = s_pc[cur];
    int ucR = s_uc[cur];            // total removed this iter (includes seed)
    int ndRaw = s_nd[cur];
    bool accept = (pcT > 64) && (2 * (ucR - 1) > pcT);  // ref uc excludes seed
    int label = count & 255;
    if (accept) count++;
    ucount -= ucR;
    if (tid == 0) { s_pc[nxt] = 0; s_uc[nxt] = 0; s_nd[nxt] = 0; }

    // ---- labels (rare: only accepted iterations) ----
    if (accept) {
      for (int c2 = wid; c2 < nc; c2 += 16) {
        unsigned long long e = s_ck[c2];
        int i0 = ((int)(e & 0x1fff)) << 5;
        int ss = (int)((e >> 13) & 0x3f);
        int lo = (int)((e >> 19) & 0x1ff);
        int h2 = (int)((e >> 28) & 0x1ff);
        int en = (int)((e >> 37) & 0x1ff);
        bool interior = (lo <= ss && h2 >= en);
        if (interior) {                 // analytic replay: no loads, no tests
          unsigned long long b0 = maskrange64(ss, min(en, 64));
          unsigned long long b1 = maskrange64(0, min(max(en - 64, 0), 64));
          unsigned long long b2 = maskrange64(0, min(max(en - 128, 0), 64));
          unsigned long long b3 = maskrange64(0, min(max(en - 192, 0), 64));
          if ((b0 >> lane) & 1ULL) outb[pk[i0 + lane].y] = label;
          if ((b1 >> lane) & 1ULL) outb[pk[i0 + 64 + lane].y] = label;
          if ((b2 >> lane) & 1ULL) outb[pk[i0 + 128 + lane].y] = label;
          if ((b3 >> lane) & 1ULL) outb[pk[i0 + 192 + lane].y] = label;
        } else if (c2 < CKBCAP) {       // cached-ballot replay
          ulonglong2 ba = s_ckbA[c2];
          ulonglong2 bb = s_ckbB[c2];
          if ((ba.x >> lane) & 1ULL) outb[pk[i0 + lane].y] = label;
          if ((ba.y >> lane) & 1ULL) outb[pk[i0 + 64 + lane].y] = label;
          if ((bb.x >> lane) & 1ULL) outb[pk[i0 + 128 + lane].y] = label;
          if ((bb.y >> lane) & 1ULL) outb[pk[i0 + 192 + lane].y] = label;
        } else {                        // overflow chunks: recompute
          #pragma unroll
          for (int g = 0; g < 4; ++g) {
            int idx = (g << 6) + lane;
            if (idx >= ss && idx < en &&
                ((idx >= lo && idx < h2) ||
                 prop_test(emb[i0 + idx], cx, cy, den0, den1, inv0, inv1)))
              outb[pk[i0 + idx].y] = label;
          }
        }
      }
    }

    // ---- rescans: only segments whose cached winner was removed ----
    if (ndRaw > DLCAP) {
      for (int s = wid; s < NSEG; s += 16)
        seg_rescan(s, V, lane, s_uncl, pk, emb, base, s_segkey, s_segci,
                   s_segaux, s_segaux2, true);
    } else {
      for (int d = wid; d < ndRaw; d += 16)
        seg_rescan(s_dlist[d], V, lane, s_uncl, pk, emb, base, s_segkey,
                   s_segci, s_segaux, s_segaux2, true);
    }
    __syncthreads();   // B2

    // ---- validate speculation, pick next winner (all waves, uniform) ----
    unsigned long long kOwn = s_segkey[sg];   // new key of old winner's segment
    if (staleArg >= 0) {
      unsigned long long kStale = s_segkey[staleArg];
      if (kStale == staleKey) {               // unchanged <=> winner alive, exact
        if (kOwn > staleKey) { sgKey = kOwn; }           // sg stays the max
        else { sg = staleArg; sgKey = staleKey; }
      } else {                                // staleArg re-keyed: full rescan
        seg_argmax(s_segkey, NSEG, lane, -1, sg, sgKey);
      }
    } else {
      // stale view had no other live segment; dirty rescans only lower keys,
      // so the only possible survivor is sg's own segment.
      if (kOwn != 0ULL) { sgKey = kOwn; } else { sg = -1; }
    }
    t++;
  }
}

// ---------------- launch ----------------

extern "C" void kernel_launch(void* const* d_in, const int* in_sizes, int n_in,
                              void* d_out, int out_size, void* d_ws, size_t ws_size,
                              hipStream_t stream) {
  const float* in = (const float*)d_in[0];
  int* out = (int*)d_out;

  size_t hist_bytes = (size_t)BATCH * NCELL * sizeof(int);
  size_t off_bytes  = (size_t)BATCH * (NCELL + 1) * sizeof(int);
  size_t cur_bytes  = (size_t)BATCH * NCELL * sizeof(int);
  size_t emb_bytes  = (size_t)BATCH * CCAP * sizeof(float2);
  size_t pk_bytes   = (size_t)BATCH * CCAP * sizeof(int2);

  size_t o_hist = 256;
  size_t o_off  = (o_hist + hist_bytes + 255) & ~(size_t)255;
  size_t o_cur  = (o_off + off_bytes + 255) & ~(size_t)255;
  size_t o_emb  = (o_cur + cur_bytes + 255) & ~(size_t)255;
  size_t o_pk   = (o_emb + emb_bytes + 255) & ~(size_t)255;
  size_t need   = o_pk + pk_bytes;

  if (ws_size < need) {
    fill_kernel<<<(out_size + 1023) / 1024, 1024, 0, stream>>>(out, 2000000, out_size);
    return;
  }

  int*    hist = (int*)((char*)d_ws + o_hist);
  int*    off  = (int*)((char*)d_ws + o_off);
  int*    cur  = (int*)((char*)d_ws + o_cur);
  float2* emb  = (float2*)((char*)d_ws + o_emb);
  int2*   pk   = (int2*)((char*)d_ws + o_pk);

  hipMemsetAsync(hist, 0, hist_bytes, stream);
  hist_kernel<<<(BATCH * NPIX) / 1024, 1024, 0, stream>>>(in, out, hist);
  scan_kernel<<<BATCH, 1024, 0, stream>>>(hist, off, cur);
  scatter_kernel<<<(BATCH * NPIX) / 1024, 1024, 0, stream>>>(in, cur, emb, pk);
  cluster_kernel<<<BATCH, 1024, 0, stream>>>(in, out, emb, pk, off);
}

// Round 9
// 793.144 us; speedup vs baseline: 1.0376x; 1.0376x over previous
//
#include <hip/hip_runtime.h>
#include <math.h>

#define BATCH 4
#define HH 512
#define WW 1024
#define NPIX (HH*WW)          // 524288 = 2^19
#define CCAP 196608           // compaction capacity per image (expected ~161.7k valid)
#define GX 64
#define GY 48
#define NCELL (GX*GY)         // 3072 cells, 0.0625 x 0.0625 over [-1,3]x[-1,2]
#define CELL 0.0625f
#define INVCELL 16.0f
#define SEGSZ 512             // pixels per argmax-cache segment
#define NSEGMAX (CCAP/SEGSZ)  // 384
#define DLCAP 2048            // dirty-segment list capacity
#define CKCAP 800             // 256-px chunk queue capacity (worst case 792)
#define CKBCAP 512            // chunks with cached proposal ballot bits

// ---------------- XLA:CPU f32 math replicas (unchanged from passing rounds) ----
__device__ __forceinline__ float xla_tanhf(float x) {
  if (fabsf(x) < 0.0004f) return x;
  float xc = fminf(fmaxf(x, -7.90531110763549805f), 7.90531110763549805f);
  float x2 = __fmul_rn(xc, xc);
  float p = -2.76076847742355e-16f;
  p = fmaf(x2, p, 2.00018790482477e-13f);
  p = fmaf(x2, p, -8.60467152213735e-11f);
  p = fmaf(x2, p, 5.12229709037114e-08f);
  p = fmaf(x2, p, 1.48572235717979e-05f);
  p = fmaf(x2, p, 6.37261928875436e-04f);
  p = fmaf(x2, p, 4.89352455891786e-03f);
  p = __fmul_rn(xc, p);
  float q = fmaf(x2, 1.19825839466702e-06f, 1.18534705686654e-04f);
  q = fmaf(x2, q, 2.26843463243900e-03f);
  q = fmaf(x2, q, 4.89352518554385e-03f);
  return __fdiv_rn(p, q);
}

__device__ __forceinline__ float xla_expf(float x) {
  float xc = fminf(fmaxf(x, -87.3365478515625f), 88.72283935546875f);
  float m = floorf(fmaf(xc, 1.44269504088896341f, 0.5f));
  float r = fmaf(m, -0.693359375f, xc);
  r = fmaf(m, 2.12194440e-4f, r);
  float r2 = __fmul_rn(r, r);
  float p = 1.9875691500e-4f;
  p = fmaf(p, r, 1.3981999507e-3f);
  p = fmaf(p, r, 8.3334519073e-3f);
  p = fmaf(p, r, 4.1665795894e-2f);
  p = fmaf(p, r, 1.6666665459e-1f);
  p = fmaf(p, r, 5.0000001201e-1f);
  float y = fmaf(r2, p, r);
  y = __fadd_rn(y, 1.0f);
  return ldexpf(y, (int)m);
}

__device__ __forceinline__ float xla_sigmoidf(float x) {
  return fmaf(0.5f, xla_tanhf(__fmul_rn(0.5f, x)), 0.5f);
}

// Proposal test — byte-identical decision logic to the passing kernels.
__device__ __forceinline__ bool prop_test(float2 e, float cx, float cy,
                                          float den0, float den1,
                                          float inv0, float inv1) {
  float d0 = __fsub_rn(e.x, cx), d1 = __fsub_rn(e.y, cy);
  float dd0 = __fmul_rn(d0, d0), dd1 = __fmul_rn(d1, d1);
  float zf = fmaf(dd0, inv0, __fmul_rn(dd1, inv1));
  if (zf < 0.6921472f) return true;
  if (zf <= 0.6941472f) {
    float t0 = __fdiv_rn(dd0, den0);
    float t1 = __fdiv_rn(dd1, den1);
    float z = __fadd_rn(t0, t1);
    return xla_expf(-z) > 0.5f;
  }
  return false;
}

__device__ __forceinline__ int cell_of_x(float ex) {
  int c = (int)((ex + 1.0f) * INVCELL);
  return min(max(c, 0), GX - 1);
}
__device__ __forceinline__ int cell_of_y(float ey) {
  int c = (int)((ey + 1.0f) * INVCELL);
  return min(max(c, 0), GY - 1);
}

// bits [a,b) of a 64-bit mask; requires 0 <= a < 64, 0 <= b <= 64, a <= b.
__device__ __forceinline__ unsigned long long maskrange64(int a, int b) {
  unsigned long long mb = (b >= 64) ? ~0ULL : ((1ULL << b) - 1ULL);
  unsigned long long ma = (1ULL << a) - 1ULL;
  return mb & ~ma;
}

// ---------------- DPP wave64 primitives (VALU-speed, replaces DS shfl chains) --
// Standard rocPRIM sequence: row_shr 1/2/4/8 then row_bcast15 (rows 1,3) and
// row_bcast31 (rows 2,3). Reduce result lands in lane 63; readlane broadcasts.
__device__ __forceinline__ unsigned wave_max_bcast_u32(unsigned x) {
  unsigned t;
  t = (unsigned)__builtin_amdgcn_update_dpp(0, (int)x, 0x111, 0xf, 0xf, false); if (t > x) x = t;
  t = (unsigned)__builtin_amdgcn_update_dpp(0, (int)x, 0x112, 0xf, 0xf, false); if (t > x) x = t;
  t = (unsigned)__builtin_amdgcn_update_dpp(0, (int)x, 0x114, 0xf, 0xf, false); if (t > x) x = t;
  t = (unsigned)__builtin_amdgcn_update_dpp(0, (int)x, 0x118, 0xf, 0xf, false); if (t > x) x = t;
  t = (unsigned)__builtin_amdgcn_update_dpp(0, (int)x, 0x142, 0xa, 0xf, false); if (t > x) x = t;
  t = (unsigned)__builtin_amdgcn_update_dpp(0, (int)x, 0x143, 0xc, 0xf, false); if (t > x) x = t;
  return (unsigned)__builtin_amdgcn_readlane((int)x, 63);
}

__device__ __forceinline__ int wave_sum_bcast_i32(int x) {
  x += __builtin_amdgcn_update_dpp(0, x, 0x111, 0xf, 0xf, false);
  x += __builtin_amdgcn_update_dpp(0, x, 0x112, 0xf, 0xf, false);
  x += __builtin_amdgcn_update_dpp(0, x, 0x114, 0xf, 0xf, false);
  x += __builtin_amdgcn_update_dpp(0, x, 0x118, 0xf, 0xf, false);
  x += __builtin_amdgcn_update_dpp(0, x, 0x142, 0xa, 0xf, false);
  x += __builtin_amdgcn_update_dpp(0, x, 0x143, 0xc, 0xf, false);
  return __builtin_amdgcn_readlane(x, 63);
}

__device__ __forceinline__ int wave_scan_incl_i32(int x) {   // per-lane inclusive
  x += __builtin_amdgcn_update_dpp(0, x, 0x111, 0xf, 0xf, false);
  x += __builtin_amdgcn_update_dpp(0, x, 0x112, 0xf, 0xf, false);
  x += __builtin_amdgcn_update_dpp(0, x, 0x114, 0xf, 0xf, false);
  x += __builtin_amdgcn_update_dpp(0, x, 0x118, 0xf, 0xf, false);
  x += __builtin_amdgcn_update_dpp(0, x, 0x142, 0xa, 0xf, false);
  x += __builtin_amdgcn_update_dpp(0, x, 0x143, 0xc, 0xf, false);
  return x;
}

// ---------------- kernels ----------------

__global__ __launch_bounds__(1024) void fill_kernel(int* out, int val, int n) {
  int i = blockIdx.x * 1024 + threadIdx.x;
  if (i < n) out[i] = val;
}

// pass A: zero output, LDS-aggregated histogram (one global atomic per block+cell)
__global__ __launch_bounds__(1024) void hist_kernel(const float* __restrict__ in,
                                                    int* __restrict__ out,
                                                    int* __restrict__ hist) {
  __shared__ int lh[NCELL];
  int tid = threadIdx.x;
  int gid = blockIdx.x * 1024 + tid;
  int b = gid >> 19;
  int p = gid & (NPIX - 1);
  for (int j = tid; j < NCELL; j += 1024) lh[j] = 0;
  __syncthreads();
  const float* base = in + (size_t)b * 5 * NPIX;
  float seed = base[(size_t)4 * NPIX + p];
  out[gid] = 0;
  if (seed > 0.5f) {
    float ox = base[p];
    float oy = base[(size_t)NPIX + p];
    int col = p & (WW - 1);
    int row = p >> 10;
    float gx = __fmul_rn((float)col, 2.0f / 1023.0f);
    float gy = __fmul_rn((float)row, 1.0f / 511.0f);
    float ex = __fadd_rn(xla_tanhf(ox), gx);
    float ey = __fadd_rn(xla_tanhf(oy), gy);
    atomicAdd(&lh[cell_of_y(ey) * GX + cell_of_x(ex)], 1);
  }
  __syncthreads();
  for (int j = tid; j < NCELL; j += 1024) {
    int c = lh[j];
    if (c) atomicAdd(&hist[b * NCELL + j], c);
  }
}

// pass B: exclusive scan of the cell counts per image (one block per image)
__global__ __launch_bounds__(1024) void scan_kernel(const int* __restrict__ hist,
                                                    int* __restrict__ off,
                                                    int* __restrict__ cursor) {
  __shared__ int s_c[NCELL];
  __shared__ int s_ps[1024];
  int b = blockIdx.x, t = threadIdx.x;
  const int* h = hist + b * NCELL;
  for (int i = t; i < NCELL; i += 1024) s_c[i] = h[i];
  __syncthreads();
  int a = s_c[3 * t], b2 = s_c[3 * t + 1], c2 = s_c[3 * t + 2];
  int th = a + b2 + c2;
  s_ps[t] = th;
  __syncthreads();
  for (int d = 1; d < 1024; d <<= 1) {
    int v = (t >= d) ? s_ps[t - d] : 0;
    __syncthreads();
    s_ps[t] += v;
    __syncthreads();
  }
  int excl = s_ps[t] - th;
  int* ob = off + b * (NCELL + 1);
  int* cb = cursor + b * NCELL;
  ob[3 * t] = excl;              cb[3 * t] = excl;
  ob[3 * t + 1] = excl + a;      cb[3 * t + 1] = excl + a;
  ob[3 * t + 2] = excl + a + b2; cb[3 * t + 2] = excl + a + b2;
  if (t == 1023) ob[NCELL] = s_ps[1023];
}

// pass C: LDS-aggregated scatter (within-cell order arbitrary; downstream is
// order-independent, tiebreak uses global pixel index)
__global__ __launch_bounds__(1024) void scatter_kernel(const float* __restrict__ in,
                                                       int* __restrict__ cursor,
                                                       float2* __restrict__ emb,
                                                       int2* __restrict__ pk) {
  __shared__ int lh[NCELL];
  __shared__ int lbase[NCELL];
  int tid = threadIdx.x;
  int gid = blockIdx.x * 1024 + tid;
  int b = gid >> 19;
  int p = gid & (NPIX - 1);
  for (int j = tid; j < NCELL; j += 1024) lh[j] = 0;
  __syncthreads();
  const float* base = in + (size_t)b * 5 * NPIX;
  float seed = base[(size_t)4 * NPIX + p];
  bool valid = seed > 0.5f;
  float ex = 0.0f, ey = 0.0f, smv = 0.0f;
  int cell = 0, sl = 0;
  if (valid) {
    float ox = base[p];
    float oy = base[(size_t)NPIX + p];
    int col = p & (WW - 1);
    int row = p >> 10;
    float gx = __fmul_rn((float)col, 2.0f / 1023.0f);
    float gy = __fmul_rn((float)row, 1.0f / 511.0f);
    ex = __fadd_rn(xla_tanhf(ox), gx);
    ey = __fadd_rn(xla_tanhf(oy), gy);
    smv = xla_sigmoidf(seed);
    cell = cell_of_y(ey) * GX + cell_of_x(ex);
    sl = atomicAdd(&lh[cell], 1);
  }
  __syncthreads();
  for (int j = tid; j < NCELL; j += 1024) {
    int c = lh[j];
    if (c) lbase[j] = atomicAdd(&cursor[b * NCELL + j], c);
  }
  __syncthreads();
  if (valid) {
    int slot = lbase[cell] + sl;
    if (slot < CCAP) {
      emb[(size_t)b * CCAP + slot] = make_float2(ex, ey);
      pk[(size_t)b * CCAP + slot]  = make_int2(__float_as_int(smv), p);
    }
  }
}

// Segment scan helper (SEGSZ=512: 8 strips of 64). DPP 32-bit-score reduce
// (exact 64-bit shfl fallback on score ties — keys are globally unique via
// ~pixel-index low bits). The unique winner lane precomputes reciprocal/radius
// aux2 so the broadcast path after argmax has no div/sqrt.
__device__ __forceinline__ void seg_rescan(int s, int V, int lane,
    const unsigned* s_uncl, const int2* __restrict__ pk,
    const float2* __restrict__ emb, const float* __restrict__ base,
    unsigned long long* s_segkey, int* s_segci, float4* s_segaux,
    float4* s_segaux2, bool checkAlive) {
  unsigned long long bk = 0ULL; int bci = -1; int bpx = 0;
  #pragma unroll
  for (int j = 0; j < 8; ++j) {
    int i = (s << 9) + (j << 6) + lane;
    if (i < V) {
      bool alive = !checkAlive || ((s_uncl[i >> 5] >> (i & 31)) & 1u);
      if (alive) {
        int2 v = pk[i];
        unsigned long long k = ((unsigned long long)(unsigned)v.x << 32) | (unsigned)(~v.y);
        if (k > bk) { bk = k; bci = i; bpx = v.y; }
      }
    }
  }
  unsigned bs = (unsigned)(bk >> 32);
  unsigned ms = wave_max_bcast_u32(bs);
  if (ms == 0u) {                       // segment fully dead
    if (lane == 0) { s_segkey[s] = 0ULL; s_segci[s] = -1; }
    return;
  }
  unsigned long long tie = __ballot(bs == ms);
  bool winner;
  if (__popcll(tie) == 1ULL) {
    winner = (bs == ms);
  } else {
    unsigned long long mk = bk;
    #pragma unroll
    for (int o = 1; o < 64; o <<= 1) {
      unsigned long long ok = __shfl_xor(mk, o);
      if (ok > mk) mk = ok;
    }
    winner = (bk == mk);                // keys unique -> exactly one lane
  }
  if (winner) {
    s_segkey[s] = bk; s_segci[s] = bci;
    float2 e = emb[bci];
    float sxv = base[(size_t)2 * NPIX + bpx];
    float syv = base[(size_t)3 * NPIX + bpx];
    float d0 = __fmul_rn(2.0f, __fmul_rn(sxv, sxv));   // ref: 2.0 * s**2
    float d1 = __fmul_rn(2.0f, __fmul_rn(syv, syv));
    s_segaux[s] = make_float4(e.x, e.y, d0, d1);
    float i0v = 1.0f / d0;              // same expr as old broadcast path
    float i1v = 1.0f / d1;
    float ryv = sqrtf(__fmul_rn(d1, 0.6971472f)) * 1.00001f;
    s_segaux2[s] = make_float4(i0v, i1v, ryv, 0.0f);
  }
}

// One workgroup per image. 2 barriers/iteration. Pass-1 work is a flat 256-px
// 32-aligned chunk queue of packed u64 descriptors
// {i0>>5 | ss<<13 | lo<<19 | h2<<28 | en<<37} (chunk-relative clamped bounds;
// [ss,en) is this chunk's owned pixel range). Queue built redundantly per wave
// (benign identical-value LDS races), consumed round-robin by all 16 waves
// with 1-deep descriptor prefetch. Interior chunks (lo<=ss && h2>=en) use
// ANALYTIC range masks — no loads, no ballots, no ballot-cache; the label
// pass re-derives their masks from the descriptor. Boundary-chunk ballots
// are cached in split arrays (s_ckbA/s_ckbB) for label replay.
__global__ __launch_bounds__(1024) void cluster_kernel(const float* __restrict__ in,
                                                       int* __restrict__ out,
                                                       const float2* __restrict__ emb_all,
                                                       const int2* __restrict__ pk_all,
                                                       const int* __restrict__ off_g) {
  __shared__ unsigned int s_uncl[CCAP / 32];            // 24 KB
  __shared__ int s_off[NCELL + 1];                      // 12 KB
  __shared__ unsigned long long s_segkey[NSEGMAX];      // 3 KB
  __shared__ int s_segci[NSEGMAX];                      // 1.5 KB
  __shared__ float4 s_segaux[NSEGMAX];                  // 6 KB
  __shared__ float4 s_segaux2[NSEGMAX];                 // 6 KB (inv0,inv1,ry)
  __shared__ int s_dlist[DLCAP];                        // 8 KB
  __shared__ unsigned long long s_ck[CKCAP];            // 6.4 KB packed chunks
  __shared__ ulonglong2 s_ckbA[CKBCAP];                 // 8 KB ballots g0,g1
  __shared__ ulonglong2 s_ckbB[CKBCAP];                 // 8 KB ballots g2,g3
  __shared__ int s_pc[2];
  __shared__ int s_uc[2];
  __shared__ int s_nd[2];

  int b = blockIdx.x;
  int tid = threadIdx.x;
  int lane = tid & 63;
  int wid = tid >> 6;
  const int* offb = off_g + b * (NCELL + 1);
  int V = offb[NCELL];
  const float2* emb = emb_all + (size_t)b * CCAP;
  const int2*   pk  = pk_all  + (size_t)b * CCAP;
  int* outb = out + (size_t)b * NPIX;
  const float* base = in + (size_t)b * 5 * NPIX;

  if (V > CCAP) {   // capacity overflow marker
    for (int i = tid; i < NPIX; i += 1024) outb[i] = 1000000;
    return;
  }
  int NSEG = (V + SEGSZ - 1) >> 9;
  int Vm1 = V - 1;

  for (int i = tid; i <= NCELL; i += 1024) s_off[i] = offb[i];
  for (int w = tid; w < CCAP / 32; w += 1024) {
    int basebit = w << 5;
    unsigned m;
    if (basebit + 32 <= V)      m = 0xffffffffu;
    else if (basebit >= V)      m = 0u;
    else                        m = (1u << (V - basebit)) - 1u;
    s_uncl[w] = m;
  }
  if (tid < 2) { s_pc[tid] = 0; s_uc[tid] = 0; s_nd[tid] = 0; }
  __syncthreads();

  // build segment caches (all pixels alive)
  for (int s = wid; s < NSEG; s += 16)
    seg_rescan(s, V, lane, s_uncl, pk, emb, base, s_segkey, s_segci, s_segaux,
               s_segaux2, false);
  __syncthreads();

  int ucount = V, count = 1, guard = 0;
  int t = 0;
  while (ucount > 64 && guard++ <= CCAP) {
    int cur = t & 1, nxt = cur ^ 1;

    // ---- wave-redundant argmax: DPP 32-bit score reduce + ballot recovery ----
    unsigned long long lk = 0ULL; int lsg = -1;
    for (int s = lane; s < NSEG; s += 64) {
      unsigned long long v = s_segkey[s];
      if (v > lk) { lk = v; lsg = s; }
    }
    unsigned ls = (unsigned)(lk >> 32);
    unsigned gs = wave_max_bcast_u32(ls);
    if (gs == 0u) break;
    float sm = __uint_as_float(gs);
    if (sm < 0.5f) break;              // ref's new_done (provably never fires)
    unsigned long long bmask = __ballot(ls == gs);
    int src, sg;
    if (__popcll(bmask) == 1ULL) {     // unique score -> that lane's key is max
      src = __builtin_ctzll(bmask);
      sg = __shfl(lsg, src);
    } else {                           // score tie: exact 64-bit fallback
      unsigned long long gk = lk;
      #pragma unroll
      for (int o = 1; o < 64; o <<= 1) {
        unsigned long long ok = __shfl_xor(gk, o);
        if (ok > gk) gk = ok;
      }
      unsigned long long bm2 = __ballot(lk == gk);   // keys unique -> one lane
      src = __builtin_ctzll(bm2);
      sg = __shfl(lsg, src);
    }

    float4 aux = s_segaux[sg];         // broadcast LDS reads
    float4 ax2 = s_segaux2[sg];
    float cx = aux.x, cy = aux.y, den0 = aux.z, den1 = aux.w;
    float inv0 = ax2.x;
    float inv1 = ax2.y;
    float ry = ax2.z;
    int r0 = cell_of_y(cy - ry);
    int r1 = cell_of_y(cy + ry);
    int nr = r1 - r0 + 1;              // <= 19

    // ---- per-lane row geometry + packed chunk queue build (redundant) ----
    int ck = 0, rs_l = 0, re_l = 0, m0_l = 0, m1_l = 0, startl = 0;
    if (lane < nr) {
      int r = r0 + lane;
      float ylo = fmaf((float)r, CELL, -1.0f);
      float dy = fmaxf(0.0f, fmaxf(ylo - cy, cy - (ylo + CELL))) * 0.999999f;
      float rem = 0.6971472f - dy * dy * inv1;
      if (rem > 0.0f) {
        float dxm = sqrtf(den0 * rem) * 1.00001f;
        int c0 = cell_of_x(cx - dxm), c1 = cell_of_x(cx + dxm);
        int rbase = r * GX;
        rs_l = s_off[rbase + c0]; re_l = s_off[rbase + c1 + 1];
        m0_l = rs_l; m1_l = rs_l;
        float dyc = fmaxf(fabsf(ylo - cy), fabsf(ylo + CELL - cy)) + 1e-5f;
        float remI = 0.6920f - dyc * dyc * inv1;
        if (remI > 0.0f) {
          float dxin = sqrtf(den0 * remI) * 0.9999f;
          int a  = (int)ceilf(fmaf(cx - dxin, INVCELL, INVCELL) + 1e-3f);
          int bb = (int)floorf(fmaf(cx + dxin, INVCELL, INVCELL) - 1e-3f) - 1;
          a = max(a, c0); bb = min(bb, c1);
          if (a <= bb) { m0_l = s_off[rbase + a]; m1_l = s_off[rbase + bb + 1]; }
        }
        startl = rs_l & ~31;
        ck = (re_l > rs_l) ? ((re_l - startl + 255) >> 8) : 0;
      }
    }
    int cum = wave_scan_incl_i32(ck);   // DPP inclusive scan (lanes>=nr add 0)
    int nc = __builtin_amdgcn_readlane(cum, 63);
    int excl = cum - ck;
    if (lane < nr && ck) {
      for (int k = 0; k < ck; ++k) {
        int i0k = startl + (k << 8);
        int ssk = max(rs_l - i0k, 0);                 // <=31, only k=0 nonzero
        int lok = min(max(m0_l - i0k, 0), 256);
        int h2k = min(max(m1_l - i0k, 0), 256);
        int enk = min(re_l - i0k, 256);
        s_ck[excl + k] = (unsigned long long)(unsigned)(i0k >> 5)
                       | ((unsigned long long)(unsigned)ssk << 13)
                       | ((unsigned long long)(unsigned)lok << 19)
                       | ((unsigned long long)(unsigned)h2k << 28)
                       | ((unsigned long long)(unsigned)enk << 37);
      }
    }

    // ---- pass 1: chunk queue, all waves round-robin, 1-deep prefetch ----
    int pc = 0, uc = 0;
    int c = wid;
    unsigned long long ed = (c < nc) ? s_ck[c] : 0ULL;
    while (c < nc) {
      int cn = c + 16;
      unsigned long long epre = (cn < nc) ? s_ck[cn] : 0ULL;
      int i0 = ((int)(ed & 0x1fff)) << 5;
      int ss = (int)((ed >> 13) & 0x3f);
      int lo = (int)((ed >> 19) & 0x1ff);
      int h2 = (int)((ed >> 28) & 0x1ff);
      int en = (int)((ed >> 37) & 0x1ff);
      bool interior = (lo <= ss && h2 >= en);
      unsigned long long bm0, bm1, bm2, bm3;
      if (interior) {                   // analytic masks: no loads, no ballots
        bm0 = maskrange64(ss, min(en, 64));
        bm1 = maskrange64(0, min(max(en - 64, 0), 64));
        bm2 = maskrange64(0, min(max(en - 128, 0), 64));
        bm3 = maskrange64(0, min(max(en - 192, 0), 64));
      } else {
        int idx1 = lane + 64, idx2 = lane + 128, idx3 = lane + 192;
        int ia = min(i0 + lane, Vm1),  ib = min(i0 + idx1, Vm1);
        int ic = min(i0 + idx2, Vm1),  id = min(i0 + idx3, Vm1);
        float2 e0 = emb[ia], e1 = emb[ib], e2 = emb[ic], e3 = emb[id];
        bool t0 = prop_test(e0, cx, cy, den0, den1, inv0, inv1);
        bool t1 = prop_test(e1, cx, cy, den0, den1, inv0, inv1);
        bool t2 = prop_test(e2, cx, cy, den0, den1, inv0, inv1);
        bool t3 = prop_test(e3, cx, cy, den0, den1, inv0, inv1);
        bool p0 = (lane >= ss && lane < en) && ((lane >= lo && lane < h2) || t0);
        bool p1 = (idx1 < en) && ((idx1 >= lo && idx1 < h2) || t1);
        bool p2 = (idx2 < en) && ((idx2 >= lo && idx2 < h2) || t2);
        bool p3 = (idx3 < en) && ((idx3 >= lo && idx3 < h2) || t3);
        bm0 = __ballot(p0);
        bm1 = __ballot(p1);
        bm2 = __ballot(p2);
        bm3 = __ballot(p3);
        if (c < CKBCAP) {
          if (lane == 0)      { ulonglong2 v; v.x = bm0; v.y = bm1; s_ckbA[c] = v; }
          else if (lane == 1) { ulonglong2 v; v.x = bm2; v.y = bm3; s_ckbB[c] = v; }
        }
      }
      if ((bm0 | bm1 | bm2 | bm3) != 0ULL && lane < 8) {
        unsigned long long bsel = (lane < 2) ? bm0 : (lane < 4) ? bm1
                                 : (lane < 6) ? bm2 : bm3;
        unsigned bits = (unsigned)(bsel >> ((lane & 1) << 5));
        pc += __popc(bits);
        if (bits) {
          unsigned tw = (unsigned)(i0 >> 5) + (unsigned)lane;
          unsigned old = atomicAnd(&s_uncl[tw], ~bits);
          unsigned remv = old & bits;
          if (remv) {
            uc += __popc(remv);
            int seg = (int)(tw >> 4);           // 512 px = 16 words
            int ciw = s_segci[seg];
            if ((ciw >> 5) == (int)tw && ((remv >> (ciw & 31)) & 1u)) {
              int pos = atomicAdd(&s_nd[cur], 1);
              if (pos < DLCAP) s_dlist[pos] = seg;
            }
          }
        }
      }
      c = cn; ed = epre;
    }
    int pcW = wave_sum_bcast_i32(pc);
    int ucW = wave_sum_bcast_i32(uc);
    if (lane == 0 && (pcW | ucW)) {
      if (pcW) atomicAdd(&s_pc[cur], pcW);
      if (ucW) atomicAdd(&s_uc[cur], ucW);
    }
    __syncthreads();   // B1

    int pcT = s_pc[cur];
    int ucR = s_uc[cur];            // total removed this iter (includes seed)
    int ndRaw = s_nd[cur];
    bool accept = (pcT > 64) && (2 * (ucR - 1) > pcT);  // ref uc excludes seed
    int label = count & 255;
    if (accept) count++;
    ucount -= ucR;
    if (tid == 0) { s_pc[nxt] = 0; s_uc[nxt] = 0; s_nd[nxt] = 0; }

    // ---- labels (rare: only accepted iterations) ----
    if (accept) {
      for (int c2 = wid; c2 < nc; c2 += 16) {
        unsigned long long e = s_ck[c2];
        int i0 = ((int)(e & 0x1fff)) << 5;
        int ss = (int)((e >> 13) & 0x3f);
        int lo = (int)((e >> 19) & 0x1ff);
        int h2 = (int)((e >> 28) & 0x1ff);
        int en = (int)((e >> 37) & 0x1ff);
        bool interior = (lo <= ss && h2 >= en);
        if (interior) {                 // analytic replay: no loads, no tests
          unsigned long long b0 = maskrange64(ss, min(en, 64));
          unsigned long long b1 = maskrange64(0, min(max(en - 64, 0), 64));
          unsigned long long b2 = maskrange64(0, min(max(en - 128, 0), 64));
          unsigned long long b3 = maskrange64(0, min(max(en - 192, 0), 64));
          if ((b0 >> lane) & 1ULL) outb[pk[i0 + lane].y] = label;
          if ((b1 >> lane) & 1ULL) outb[pk[i0 + 64 + lane].y] = label;
          if ((b2 >> lane) & 1ULL) outb[pk[i0 + 128 + lane].y] = label;
          if ((b3 >> lane) & 1ULL) outb[pk[i0 + 192 + lane].y] = label;
        } else if (c2 < CKBCAP) {       // cached-ballot replay
          ulonglong2 ba = s_ckbA[c2];
          ulonglong2 bb = s_ckbB[c2];
          if ((ba.x >> lane) & 1ULL) outb[pk[i0 + lane].y] = label;
          if ((ba.y >> lane) & 1ULL) outb[pk[i0 + 64 + lane].y] = label;
          if ((bb.x >> lane) & 1ULL) outb[pk[i0 + 128 + lane].y] = label;
          if ((bb.y >> lane) & 1ULL) outb[pk[i0 + 192 + lane].y] = label;
        } else {                        // overflow chunks: recompute
          #pragma unroll
          for (int g = 0; g < 4; ++g) {
            int idx = (g << 6) + lane;
            if (idx >= ss && idx < en &&
                ((idx >= lo && idx < h2) ||
                 prop_test(emb[i0 + idx], cx, cy, den0, den1, inv0, inv1)))
              outb[pk[i0 + idx].y] = label;
          }
        }
      }
    }

    // ---- rescans: only segments whose cached winner was removed ----
    if (ndRaw > DLCAP) {
      for (int s = wid; s < NSEG; s += 16)
        seg_rescan(s, V, lane, s_uncl, pk, emb, base, s_segkey, s_segci,
                   s_segaux, s_segaux2, true);
    } else {
      for (int d = wid; d < ndRaw; d += 16)
        seg_rescan(s_dlist[d], V, lane, s_uncl, pk, emb, base, s_segkey,
                   s_segci, s_segaux, s_segaux2, true);
    }
    __syncthreads();   // B2
    t++;
  }
}

// ---------------- launch ----------------

extern "C" void kernel_launch(void* const* d_in, const int* in_sizes, int n_in,
                              void* d_out, int out_size, void* d_ws, size_t ws_size,
                              hipStream_t stream) {
  const float* in = (const float*)d_in[0];
  int* out = (int*)d_out;

  size_t hist_bytes = (size_t)BATCH * NCELL * sizeof(int);
  size_t off_bytes  = (size_t)BATCH * (NCELL + 1) * sizeof(int);
  size_t cur_bytes  = (size_t)BATCH * NCELL * sizeof(int);
  size_t emb_bytes  = (size_t)BATCH * CCAP * sizeof(float2);
  size_t pk_bytes   = (size_t)BATCH * CCAP * sizeof(int2);

  size_t o_hist = 256;
  size_t o_off  = (o_hist + hist_bytes + 255) & ~(size_t)255;
  size_t o_cur  = (o_off + off_bytes + 255) & ~(size_t)255;
  size_t o_emb  = (o_cur + cur_bytes + 255) & ~(size_t)255;
  size_t o_pk   = (o_emb + emb_bytes + 255) & ~(size_t)255;
  size_t need   = o_pk + pk_bytes;

  if (ws_size < need) {
    fill_kernel<<<(out_size + 1023) / 1024, 1024, 0, stream>>>(out, 2000000, out_size);
    return;
  }

  int*    hist = (int*)((char*)d_ws + o_hist);
  int*    off  = (int*)((char*)d_ws + o_off);
  int*    cur  = (int*)((char*)d_ws + o_cur);
  float2* emb  = (float2*)((char*)d_ws + o_emb);
  int2*   pk   = (int2*)((char*)d_ws + o_pk);

  hipMemsetAsync(hist, 0, hist_bytes, stream);
  hist_kernel<<<(BATCH * NPIX) / 1024, 1024, 0, stream>>>(in, out, hist);
  scan_kernel<<<BATCH, 1024, 0, stream>>>(hist, off, cur);
  scatter_kernel<<<(BATCH * NPIX) / 1024, 1024, 0, stream>>>(in, cur, emb, pk);
  cluster_kernel<<<BATCH, 1024, 0, stream>>>(in, out, emb, pk, off);
}